// Round 10
// baseline (1024.309 us; speedup 1.0000x reference)
//
#include <hip/hip_runtime.h>
#include <stdint.h>

// GCN 2-layer: h1 = relu(Anorm @ (x@W1) + b1); out = Anorm @ (h1@W2) + b2
// R10: R9 with compile fix (ext_vector f32x4 for nontemporal loads).
//     gemm1 = ZERO-LDS streaming GEMM: A fragments straight from x
//     (nontemporal) into regs, B fragments straight from L2-resident W1T
//     quarter. No barriers, no staging; waves desync freely.

namespace {
constexpr int NN = 16384;     // nodes
constexpr int CH = 256;       // hidden channels
constexpr int KC = 16;        // classes
constexpr int NE = 524288;    // edges
constexpr int KD = 16384;     // input feature dim
constexpr int KSPLIT = 4;
constexpr int NJ = KD / KSPLIT / 32;   // 128 K-steps

// workspace byte offsets
constexpr size_t OFF_W1T  = 0;            // bf16 [256][16384]        = 8 MiB
constexpr size_t OFF_HP   = 8388608;      // f32  [4][16384][256]     = 64 MiB
constexpr size_t OFF_HB   = 75497472;     // bf16 [16384][256]        = 8 MiB
constexpr size_t OFF_OUT1 = 83886080;     // f32  [16384][256]        = 16 MiB
constexpr size_t OFF_H2   = 100663296;    // f32  [16384][16]         = 1 MiB
constexpr size_t OFF_DEG  = 101711872;    // f32  [16384]
constexpr size_t OFF_CNT  = 101777408;    // i32  [16384] (contiguous w/ DEG)
constexpr size_t OFF_DINV = 101842944;    // f32  [16384]
constexpr size_t OFF_ROWP = 101908480;    // i32  [16385]
constexpr size_t OFF_CUR  = 102039552;    // i32  [16384]
constexpr size_t OFF_COLS = 102105088;    // i32  [E] = 2 MiB
constexpr size_t OFF_NRM  = 104202240;    // f32  [E] = 2 MiB
}

typedef __attribute__((ext_vector_type(8))) short bf16x8;
typedef __attribute__((ext_vector_type(4))) float f32x4;

__device__ __forceinline__ unsigned short f2bf(float f) {
  unsigned int u = __builtin_bit_cast(unsigned int, f);
  u += 0x7fffu + ((u >> 16) & 1u);
  return (unsigned short)(u >> 16);
}
__device__ __forceinline__ float bf2f(unsigned short v) {
  unsigned int u = ((unsigned int)v) << 16;
  return __builtin_bit_cast(float, u);
}

// ---- W1 [16384][256] f32  ->  W1T [256][16384] bf16 ----
__global__ __launch_bounds__(256)
void k_w1t(const float* __restrict__ w1, unsigned short* __restrict__ w1t) {
  __shared__ float tile[64][65];
  const int t = threadIdx.x;
  const int kb = blockIdx.x * 64;
  const int nb = blockIdx.y * 64;
  const int r = t >> 6;
  const int c = t & 63;
#pragma unroll
  for (int i = 0; i < 16; ++i)
    tile[i * 4 + r][c] = w1[(size_t)(kb + i * 4 + r) * CH + nb + c];
  __syncthreads();
#pragma unroll
  for (int i = 0; i < 16; ++i)
    w1t[(size_t)(nb + i * 4 + r) * KD + kb + c] = f2bf(tile[c][i * 4 + r]);
}

// ---- degree + in-edge histogram ----
__global__ __launch_bounds__(256)
void k_deg(const int* __restrict__ dst, const float* __restrict__ ew,
           float* __restrict__ deg, int* __restrict__ cnt) {
  const int e = blockIdx.x * 256 + threadIdx.x;
  const int d = dst[e];
  atomicAdd(&deg[d], ew[e]);
  atomicAdd(&cnt[d], 1);
}

// ---- exclusive scan of cnt -> rowp/cursor, plus dinv (single block) ----
__global__ __launch_bounds__(256)
void k_scan(const int* __restrict__ cnt, const float* __restrict__ deg,
            int* __restrict__ rowp, int* __restrict__ curs,
            float* __restrict__ dinv) {
  __shared__ int ps[256];
  const int t = threadIdx.x;
  const int base = t * 64;
  int s = 0;
  for (int j = 0; j < 64; ++j) s += cnt[base + j];
  ps[t] = s;
  for (int j = 0; j < 64; ++j)
    dinv[base + j] = rsqrtf(deg[base + j] + 1.0f);   // +1 = self-loop weight
  __syncthreads();
  int v = s;
  for (int off = 1; off < 256; off <<= 1) {
    int u = (t >= off) ? ps[t - off] : 0;
    __syncthreads();
    v += u;
    ps[t] = v;
    __syncthreads();
  }
  int run = v - s;
  for (int j = 0; j < 64; ++j) {
    int c = cnt[base + j];
    rowp[base + j] = run;
    curs[base + j] = run;
    run += c;
  }
  if (t == 255) rowp[NN] = run;
}

// ---- CSR fill: edge -> (src, norm) bucketed by dst ----
__global__ __launch_bounds__(256)
void k_fill(const int* __restrict__ src, const int* __restrict__ dst,
            const float* __restrict__ ew, const float* __restrict__ dinv,
            int* __restrict__ curs, int* __restrict__ cols, float* __restrict__ nrm) {
  const int e = blockIdx.x * 256 + threadIdx.x;
  const int s = src[e], d = dst[e];
  const int pos = atomicAdd(&curs[d], 1);
  cols[pos] = s;
  nrm[pos] = dinv[s] * ew[e] * dinv[d];
}

// fragment set: A (2 m-frags, fp32 raw) + B (8 n-frags, bf16)
struct Frag {
  f32x4 a[4];      // [mi*2 + half]
  bf16x8 b[8];     // [ni]
};

// ---- GEMM1: hp[kb][16384][256] = x[:, kb-quarter] @ W1T[kb-quarter] ----
// Zero-LDS streaming: grid 1024 (2 blocks/CU), block = 4 waves, wave owns
// 32 rows x 128 cols. All operands loaded per K-step straight to registers.
__global__ __launch_bounds__(256, 2)
void k_gemm1(const float* __restrict__ x, const unsigned short* __restrict__ w1t,
             float* __restrict__ hp) {
  const int tid  = threadIdx.x;
  const int lane = tid & 63;
  const int wave = tid >> 6;
  const int wm   = wave >> 1;   // 0..1 -> M half (32 rows)
  const int wn   = wave & 1;    // 0..1 -> N half (128 cols)

  const int bid  = blockIdx.x;
  const int xcd  = bid & 7;
  const int slot = bid >> 3;                   // 0..127
  const int kb   = xcd >> 1;                   // 0..3, constant per XCD
  const int bm0  = (slot * 2 + (xcd & 1)) * 64;
  const int koff = kb * (KD / KSPLIT);

  const int fr = lane & 15, fg = lane >> 4;

  // A: rows bm0 + wm*32 + mi*16 + fr, k-window fg*8 (8 f32 = 2 f32x4)
  const float* aP = x + (size_t)(bm0 + wm * 32 + fr) * KD + koff + fg * 8;
  // B: rows wn*128 + ni*16 + fr (col of output), same k-window (8 bf16 = 16B)
  const unsigned short* bP = w1t + (size_t)(wn * 128 + fr) * KD + koff + fg * 8;

  f32x4 acc[2][8] = {};

  auto LOAD = [&](int j, Frag& f) {
    const float* ap = aP + j * 32;
#pragma unroll
    for (int mi = 0; mi < 2; ++mi) {
      const float* r = ap + (size_t)(mi * 16) * KD;
      f.a[mi * 2 + 0] = __builtin_nontemporal_load(reinterpret_cast<const f32x4*>(r));
      f.a[mi * 2 + 1] = __builtin_nontemporal_load(reinterpret_cast<const f32x4*>(r + 4));
    }
    const unsigned short* bp = bP + j * 32;
#pragma unroll
    for (int ni = 0; ni < 8; ++ni)
      f.b[ni] = *reinterpret_cast<const bf16x8*>(bp + (size_t)(ni * 16) * KD);
  };
  auto COMPUTE = [&](const Frag& f) {
#pragma unroll
    for (int mi = 0; mi < 2; ++mi) {
      const f32x4 lo = f.a[mi * 2 + 0];
      const f32x4 hi = f.a[mi * 2 + 1];
      bf16x8 am;
      am[0] = (short)f2bf(lo[0]); am[1] = (short)f2bf(lo[1]);
      am[2] = (short)f2bf(lo[2]); am[3] = (short)f2bf(lo[3]);
      am[4] = (short)f2bf(hi[0]); am[5] = (short)f2bf(hi[1]);
      am[6] = (short)f2bf(hi[2]); am[7] = (short)f2bf(hi[3]);
#pragma unroll
      for (int ni = 0; ni < 8; ++ni)
        acc[mi][ni] = __builtin_amdgcn_mfma_f32_16x16x32_bf16(am, f.b[ni], acc[mi][ni], 0, 0, 0);
    }
  };

  Frag s0, s1;
  LOAD(0, s0);
  for (int j = 0; j < NJ; j += 2) {           // NJ = 128 (even)
    if (j + 1 < NJ) LOAD(j + 1, s1);
    COMPUTE(s0);
    if (j + 2 < NJ) LOAD(j + 2, s0);
    if (j + 1 < NJ) COMPUTE(s1);
  }

  float* hpo = hp + (size_t)kb * NN * CH;
#pragma unroll
  for (int mi = 0; mi < 2; ++mi)
#pragma unroll
    for (int ni = 0; ni < 8; ++ni)
#pragma unroll
      for (int r = 0; r < 4; ++r) {
        const int m = bm0 + wm * 32 + mi * 16 + fg * 4 + r;
        const int n = wn * 128 + ni * 16 + fr;
        __builtin_nontemporal_store(acc[mi][ni][r], &hpo[(size_t)m * CH + n]);
      }
}

// ---- reduce 4 partials -> h bf16 ----
__global__ __launch_bounds__(256)
void k_hred(const float* __restrict__ hp, unsigned short* __restrict__ hb) {
  const size_t i = ((size_t)blockIdx.x * 256 + threadIdx.x) * 8;
  float s[8];
#pragma unroll
  for (int j = 0; j < 8; ++j) s[j] = 0.f;
#pragma unroll
  for (int p = 0; p < KSPLIT; ++p) {
    const float* q = hp + (size_t)p * NN * CH + i;
    const float4 v0 = *reinterpret_cast<const float4*>(q);
    const float4 v1 = *reinterpret_cast<const float4*>(q + 4);
    s[0] += v0.x; s[1] += v0.y; s[2] += v0.z; s[3] += v0.w;
    s[4] += v1.x; s[5] += v1.y; s[6] += v1.z; s[7] += v1.w;
  }
  bf16x8 o;
#pragma unroll
  for (int j = 0; j < 8; ++j) o[j] = (short)f2bf(s[j]);
  *reinterpret_cast<bf16x8*>(hb + i) = o;
}

// ---- aggregation 1 (+b1, relu): wave-parallel edges, lane owns 4 channels ----
__global__ __launch_bounds__(256)
void k_agg1(const unsigned short* __restrict__ hb, const int* __restrict__ rowp,
            const int* __restrict__ cols, const float* __restrict__ nrm,
            const float* __restrict__ dinv, const float* __restrict__ b1,
            float* __restrict__ out1) {
  __shared__ float red[4][256];
  const int i = blockIdx.x;
  const int t = threadIdx.x;
  const int w = t >> 6, l = t & 63;
  const int beg = rowp[i], end = rowp[i + 1];
  float a0 = 0.f, a1 = 0.f, a2 = 0.f, a3 = 0.f;
  int e = beg + w;
  for (; e + 4 < end; e += 8) {
    const int s0 = cols[e], s1 = cols[e + 4];
    const float n0 = nrm[e], n1 = nrm[e + 4];
    const ushort4 h0 = *reinterpret_cast<const ushort4*>(hb + (size_t)s0 * CH + l * 4);
    const ushort4 h1 = *reinterpret_cast<const ushort4*>(hb + (size_t)s1 * CH + l * 4);
    a0 += n0 * bf2f(h0.x) + n1 * bf2f(h1.x);
    a1 += n0 * bf2f(h0.y) + n1 * bf2f(h1.y);
    a2 += n0 * bf2f(h0.z) + n1 * bf2f(h1.z);
    a3 += n0 * bf2f(h0.w) + n1 * bf2f(h1.w);
  }
  if (e < end) {
    const int s0 = cols[e];
    const float n0 = nrm[e];
    const ushort4 h0 = *reinterpret_cast<const ushort4*>(hb + (size_t)s0 * CH + l * 4);
    a0 += n0 * bf2f(h0.x); a1 += n0 * bf2f(h0.y);
    a2 += n0 * bf2f(h0.z); a3 += n0 * bf2f(h0.w);
  }
  *reinterpret_cast<float4*>(&red[w][l * 4]) = make_float4(a0, a1, a2, a3);
  __syncthreads();
  const float di = dinv[i];
  float sum = red[0][t] + red[1][t] + red[2][t] + red[3][t]
            + di * di * bf2f(hb[(size_t)i * CH + t]) + b1[t];
  out1[(size_t)i * CH + t] = fmaxf(sum, 0.0f);
}

// ---- GEMM2: h2[16384][16] = out1 @ W2[256][16] ----
__global__ __launch_bounds__(256)
void k_gemm2(const float* __restrict__ out1, const float* __restrict__ w2,
             float* __restrict__ h2) {
  __shared__ float xs[16][256];
  __shared__ float ws[256 * 16];
  const int t = threadIdx.x;
  const int n0 = blockIdx.x * 16;
#pragma unroll
  for (int i = 0; i < 16; ++i) ws[i * 256 + t] = w2[i * 256 + t];
#pragma unroll
  for (int i = 0; i < 16; ++i) xs[i][t] = out1[(size_t)(n0 + i) * CH + t];
  __syncthreads();
  const int node = t >> 4, k = t & 15;
  float acc = 0.f;
#pragma unroll 8
  for (int c = 0; c < 256; ++c) acc += xs[node][c] * ws[c * 16 + k];
  h2[(size_t)(n0 + node) * KC + k] = acc;
}

// ---- aggregation 2 (+b2): one wave per node ----
__global__ __launch_bounds__(256)
void k_agg2(const float* __restrict__ h2, const int* __restrict__ rowp,
            const int* __restrict__ cols, const float* __restrict__ nrm,
            const float* __restrict__ dinv, const float* __restrict__ b2,
            float* __restrict__ out) {
  const int i = blockIdx.x * 4 + (threadIdx.x >> 6);
  const int lane = threadIdx.x & 63;
  const int k = lane & 15, g = lane >> 4;
  const int beg = rowp[i], end = rowp[i + 1];
  float acc = 0.f;
  for (int e = beg + g; e < end; e += 4)
    acc += nrm[e] * h2[(size_t)cols[e] * KC + k];
  acc += __shfl_xor(acc, 16);
  acc += __shfl_xor(acc, 32);
  if (g == 0) {
    const float di = dinv[i];
    out[(size_t)i * KC + k] = acc + di * di * h2[(size_t)i * KC + k] + b2[k];
  }
}

extern "C" void kernel_launch(void* const* d_in, const int* in_sizes, int n_in,
                              void* d_out, int out_size, void* d_ws, size_t ws_size,
                              hipStream_t stream) {
  const float* x  = (const float*)d_in[0];
  const int*   ei = (const int*)d_in[1];
  const float* ew = (const float*)d_in[2];
  const float* w1 = (const float*)d_in[3];
  const float* b1 = (const float*)d_in[4];
  const float* w2 = (const float*)d_in[5];
  const float* b2 = (const float*)d_in[6];
  const int* src = ei;
  const int* dst = ei + NE;

  uint8_t* ws = (uint8_t*)d_ws;
  unsigned short* w1t = (unsigned short*)(ws + OFF_W1T);
  float* hp   = (float*)(ws + OFF_HP);
  unsigned short* hb = (unsigned short*)(ws + OFF_HB);
  float* out1 = (float*)(ws + OFF_OUT1);
  float* h2   = (float*)(ws + OFF_H2);
  float* deg  = (float*)(ws + OFF_DEG);
  int*   cnt  = (int*)(ws + OFF_CNT);
  float* dinv = (float*)(ws + OFF_DINV);
  int*   rowp = (int*)(ws + OFF_ROWP);
  int*   curs = (int*)(ws + OFF_CUR);
  int*   cols = (int*)(ws + OFF_COLS);
  float* nrm  = (float*)(ws + OFF_NRM);
  float* out  = (float*)d_out;

  hipMemsetAsync(ws + OFF_DEG, 0, 131072, stream);  // deg + cnt

  k_w1t <<<dim3(256, 4), 256, 0, stream>>>(w1, w1t);
  k_deg <<<NE / 256, 256, 0, stream>>>(dst, ew, deg, cnt);
  k_scan<<<1, 256, 0, stream>>>(cnt, deg, rowp, curs, dinv);
  k_fill<<<NE / 256, 256, 0, stream>>>(src, dst, ew, dinv, curs, cols, nrm);
  k_gemm1<<<1024, 256, 0, stream>>>(x, w1t, hp);
  k_hred<<<NN * CH / (256 * 8), 256, 0, stream>>>(hp, hb);
  k_agg1<<<NN, 256, 0, stream>>>(hb, rowp, cols, nrm, dinv, b1, out1);
  k_gemm2<<<NN / 16, 256, 0, stream>>>(out1, w2, h2);
  k_agg2<<<NN / 4, 256, 0, stream>>>(h2, rowp, cols, nrm, dinv, b2, out);
}

// Round 11
// 505.400 us; speedup vs baseline: 2.0267x; 2.0267x over previous
//
#include <hip/hip_runtime.h>
#include <stdint.h>

// GCN 2-layer: h1 = relu(Anorm @ (x@W1) + b1); out = Anorm @ (h1@W2) + b2
// R11: gemm1 v3. B pre-packed FRAGMENT-MAJOR (k_bpack) -> wave B-frag load is
//     one coalesced dwordx4 from L2-resident panel, no LDS for B. A staged
//     f32 via global_load_lds (swizzled src, linear dest), cvt_pk at frag
//     read. 16KB LDS/block, 4 blocks/CU (regs<=128 via launch_bounds(256,4)).

namespace {
constexpr int NN = 16384;     // nodes
constexpr int CH = 256;       // hidden channels
constexpr int KC = 16;        // classes
constexpr int NE = 524288;    // edges
constexpr int KD = 16384;     // input feature dim
constexpr int KSPLIT = 4;
constexpr int NT = KD / KSPLIT / 32;   // 128 K-steps per block

// workspace byte offsets
constexpr size_t OFF_BP   = 0;            // bf16 frag-major [4][128][16][64][8] = 8 MiB
constexpr size_t OFF_HP   = 8388608;      // f32  [4][16384][256]     = 64 MiB
constexpr size_t OFF_HB   = 75497472;     // bf16 [16384][256]        = 8 MiB
constexpr size_t OFF_OUT1 = 83886080;     // f32  [16384][256]        = 16 MiB
constexpr size_t OFF_H2   = 100663296;    // f32  [16384][16]         = 1 MiB
constexpr size_t OFF_DEG  = 101711872;    // f32  [16384]
constexpr size_t OFF_CNT  = 101777408;    // i32  [16384] (contiguous w/ DEG)
constexpr size_t OFF_DINV = 101842944;    // f32  [16384]
constexpr size_t OFF_ROWP = 101908480;    // i32  [16385]
constexpr size_t OFF_CUR  = 102039552;    // i32  [16384]
constexpr size_t OFF_COLS = 102105088;    // i32  [E] = 2 MiB
constexpr size_t OFF_NRM  = 104202240;    // f32  [E] = 2 MiB
}

typedef __attribute__((ext_vector_type(8))) short bf16x8;
typedef __attribute__((ext_vector_type(4))) float f32x4;
typedef __attribute__((ext_vector_type(4))) unsigned int u32x4;

__device__ __forceinline__ unsigned short f2bf(float f) {
  unsigned int u = __builtin_bit_cast(unsigned int, f);
  u += 0x7fffu + ((u >> 16) & 1u);
  return (unsigned short)(u >> 16);
}
__device__ __forceinline__ float bf2f(unsigned short v) {
  unsigned int u = ((unsigned int)v) << 16;
  return __builtin_bit_cast(float, u);
}
__device__ __forceinline__ unsigned int cvt_pk(float lo, float hi) {
  unsigned int r;
  asm("v_cvt_pk_bf16_f32 %0, %1, %2" : "=v"(r) : "v"(lo), "v"(hi));
  return r;
}

// ---- B pre-pack: W1 [16384][256] f32 -> Bp fragment-major bf16 ----
// Bp[kb][j][ni][lane] (16B per lane): lane (fr,fg) holds W1[k0+j*32+fg*8+m][ni*16+fr]
__global__ __launch_bounds__(256)
void k_bpack(const float* __restrict__ w1, unsigned short* __restrict__ bp) {
  __shared__ float tile[64][65];
  const int t = threadIdx.x;
  const int k0 = blockIdx.x * 64;   // k tile
  const int n0 = blockIdx.y * 64;   // n tile
  const int r = t >> 6;
  const int c = t & 63;
#pragma unroll
  for (int i = 0; i < 16; ++i)
    tile[i * 4 + r][c] = w1[(size_t)(k0 + i * 4 + r) * CH + n0 + c];
  __syncthreads();
#pragma unroll
  for (int rep = 0; rep < 2; ++rep) {
    const int idx = rep * 256 + t;
    const int lane = idx & 63;
    const int nip  = (idx >> 6) & 3;     // ni within tile
    const int jp   = (idx >> 8) & 1;     // j-step within tile (32 k each)
    const int fr = lane & 15, fg = lane >> 4;
    const int kglob = k0 + jp * 32;
    const int kb = kglob >> 12;
    const int j  = (kglob & 4095) >> 5;
    const int ni = (n0 >> 4) + nip;
    float v[8];
#pragma unroll
    for (int m = 0; m < 8; ++m) v[m] = tile[jp * 32 + fg * 8 + m][nip * 16 + fr];
    u32x4 p;
    p.x = cvt_pk(v[0], v[1]); p.y = cvt_pk(v[2], v[3]);
    p.z = cvt_pk(v[4], v[5]); p.w = cvt_pk(v[6], v[7]);
    *reinterpret_cast<u32x4*>(bp + ((((size_t)kb * 128 + j) * 16 + ni) * 64 + lane) * 8) = p;
  }
}

// ---- degree + in-edge histogram ----
__global__ __launch_bounds__(256)
void k_deg(const int* __restrict__ dst, const float* __restrict__ ew,
           float* __restrict__ deg, int* __restrict__ cnt) {
  const int e = blockIdx.x * 256 + threadIdx.x;
  const int d = dst[e];
  atomicAdd(&deg[d], ew[e]);
  atomicAdd(&cnt[d], 1);
}

// ---- exclusive scan of cnt -> rowp/cursor, plus dinv (single block) ----
__global__ __launch_bounds__(256)
void k_scan(const int* __restrict__ cnt, const float* __restrict__ deg,
            int* __restrict__ rowp, int* __restrict__ curs,
            float* __restrict__ dinv) {
  __shared__ int ps[256];
  const int t = threadIdx.x;
  const int base = t * 64;
  int s = 0;
  for (int j = 0; j < 64; ++j) s += cnt[base + j];
  ps[t] = s;
  for (int j = 0; j < 64; ++j)
    dinv[base + j] = rsqrtf(deg[base + j] + 1.0f);   // +1 = self-loop weight
  __syncthreads();
  int v = s;
  for (int off = 1; off < 256; off <<= 1) {
    int u = (t >= off) ? ps[t - off] : 0;
    __syncthreads();
    v += u;
    ps[t] = v;
    __syncthreads();
  }
  int run = v - s;
  for (int j = 0; j < 64; ++j) {
    int c = cnt[base + j];
    rowp[base + j] = run;
    curs[base + j] = run;
    run += c;
  }
  if (t == 255) rowp[NN] = run;
}

// ---- CSR fill: edge -> (src, norm) bucketed by dst ----
__global__ __launch_bounds__(256)
void k_fill(const int* __restrict__ src, const int* __restrict__ dst,
            const float* __restrict__ ew, const float* __restrict__ dinv,
            int* __restrict__ curs, int* __restrict__ cols, float* __restrict__ nrm) {
  const int e = blockIdx.x * 256 + threadIdx.x;
  const int s = src[e], d = dst[e];
  const int pos = atomicAdd(&curs[d], 1);
  cols[pos] = s;
  nrm[pos] = dinv[s] * ew[e] * dinv[d];
}

// ---- GEMM1: hp[kb][16384][256] = x[:, kb-quarter] @ W1[kb-quarter] ----
// BM=64 BN=256 BK=32, KSPLIT=4, grid 1024 = 4 blocks/CU (16 KB LDS, <=128 reg).
// A: global_load_lds f32 double-buffer (swizzled src). B: direct coalesced
// frag loads from Bp (L2-resident). Barrier drain covered by 3 other blocks.
__global__ __launch_bounds__(256, 4)
void k_gemm1(const float* __restrict__ x, const unsigned short* __restrict__ bp,
             float* __restrict__ hp) {
  __shared__ __align__(16) uint8_t As[2][8192];   // 64 rows x 32 f32

  const int tid  = threadIdx.x;
  const int lane = tid & 63;
  const int wave = tid >> 6;

  const int bid  = blockIdx.x;
  const int xcd  = bid & 7;
  const int slot = bid >> 3;                   // 0..127
  const int kb   = xcd >> 1;                   // 0..3, constant per XCD
  const int bm0  = (slot * 2 + (xcd & 1)) * 64;
  const int koff = kb * (KD / KSPLIT);

  // A staging: wave w instr i (i=0,1): rows 16w+8i + (l>>3); source chunk
  // swizzled cs = (l&7)^(l>>3); LDS dest linear (slot s of row r = chunk s^(r&7))
  const float* asrc0 = x + (size_t)(bm0 + 16 * wave + (lane >> 3)) * KD + koff
                         + (((lane & 7) ^ (lane >> 3)) << 2);
  const float* asrc1 = asrc0 + (size_t)8 * KD;

  // B source: fragment-major panel for this kb
  const unsigned short* bbase = bp + ((size_t)kb * 128 * 16 + (size_t)wave * 4) * 512
                                   + lane * 8;   // +j*16*512, +nn*512

  const int fr = lane & 15, fg = lane >> 4;

  f32x4 acc[4][4] = {};

  auto GLDSA = [&](int j, int buf) {
    const float* p0 = asrc0 + (size_t)j * 32;
    const float* p1 = asrc1 + (size_t)j * 32;
    __builtin_amdgcn_global_load_lds(
        (const __attribute__((address_space(1))) void*)p0,
        (__attribute__((address_space(3))) void*)(&As[buf][(wave * 2 + 0) * 1024]), 16, 0, 0);
    __builtin_amdgcn_global_load_lds(
        (const __attribute__((address_space(1))) void*)p1,
        (__attribute__((address_space(3))) void*)(&As[buf][(wave * 2 + 1) * 1024]), 16, 0, 0);
  };

  GLDSA(0, 0);
  __syncthreads();

  for (int j = 0; j < NT; ++j) {
    if (j + 1 < NT) GLDSA(j + 1, (j + 1) & 1);
    // B fragments: coalesced 1KB loads from L2
    const unsigned short* bj = bbase + (size_t)j * 16 * 512;
    bf16x8 bfr[4];
#pragma unroll
    for (int nn = 0; nn < 4; ++nn)
      bfr[nn] = *reinterpret_cast<const bf16x8*>(bj + (size_t)nn * 512);
    // A fragments from LDS (f32, swizzled slots), cvt_pk -> bf16
    const uint8_t* Ab = &As[j & 1][0];
    __builtin_amdgcn_s_setprio(1);
#pragma unroll
    for (int mi = 0; mi < 4; ++mi) {
      const int rr = mi * 16 + fr;
      const int base = rr * 128;
      const f32x4 lo = *reinterpret_cast<const f32x4*>(Ab + base + (((fg * 2) ^ (rr & 7)) << 4));
      const f32x4 hi = *reinterpret_cast<const f32x4*>(Ab + base + (((fg * 2 + 1) ^ (rr & 7)) << 4));
      u32x4 p;
      p.x = cvt_pk(lo[0], lo[1]); p.y = cvt_pk(lo[2], lo[3]);
      p.z = cvt_pk(hi[0], hi[1]); p.w = cvt_pk(hi[2], hi[3]);
      const bf16x8 af = __builtin_bit_cast(bf16x8, p);
#pragma unroll
      for (int nn = 0; nn < 4; ++nn)
        acc[mi][nn] = __builtin_amdgcn_mfma_f32_16x16x32_bf16(af, bfr[nn], acc[mi][nn], 0, 0, 0);
    }
    __builtin_amdgcn_s_setprio(0);
    if (j + 1 < NT) __syncthreads();   // drains glds(j+1); 3 other blocks cover
  }

  float* hpo = hp + (size_t)kb * NN * CH;
#pragma unroll
  for (int mi = 0; mi < 4; ++mi)
#pragma unroll
    for (int nn = 0; nn < 4; ++nn)
#pragma unroll
      for (int r = 0; r < 4; ++r) {
        const int m = bm0 + mi * 16 + fg * 4 + r;
        const int n = wave * 64 + nn * 16 + fr;
        __builtin_nontemporal_store(acc[mi][nn][r], &hpo[(size_t)m * CH + n]);
      }
}

// ---- reduce 4 partials -> h bf16 ----
__global__ __launch_bounds__(256)
void k_hred(const float* __restrict__ hp, unsigned short* __restrict__ hb) {
  const size_t i = ((size_t)blockIdx.x * 256 + threadIdx.x) * 8;
  float s[8];
#pragma unroll
  for (int j = 0; j < 8; ++j) s[j] = 0.f;
#pragma unroll
  for (int p = 0; p < KSPLIT; ++p) {
    const float* q = hp + (size_t)p * NN * CH + i;
    const float4 v0 = *reinterpret_cast<const float4*>(q);
    const float4 v1 = *reinterpret_cast<const float4*>(q + 4);
    s[0] += v0.x; s[1] += v0.y; s[2] += v0.z; s[3] += v0.w;
    s[4] += v1.x; s[5] += v1.y; s[6] += v1.z; s[7] += v1.w;
  }
  bf16x8 o;
#pragma unroll
  for (int j = 0; j < 8; ++j) o[j] = (short)f2bf(s[j]);
  *reinterpret_cast<bf16x8*>(hb + i) = o;
}

// ---- aggregation 1 (+b1, relu): wave-parallel edges, lane owns 4 channels ----
__global__ __launch_bounds__(256)
void k_agg1(const unsigned short* __restrict__ hb, const int* __restrict__ rowp,
            const int* __restrict__ cols, const float* __restrict__ nrm,
            const float* __restrict__ dinv, const float* __restrict__ b1,
            float* __restrict__ out1) {
  __shared__ float red[4][256];
  const int i = blockIdx.x;
  const int t = threadIdx.x;
  const int w = t >> 6, l = t & 63;
  const int beg = rowp[i], end = rowp[i + 1];
  float a0 = 0.f, a1 = 0.f, a2 = 0.f, a3 = 0.f;
  int e = beg + w;
  for (; e + 4 < end; e += 8) {
    const int s0 = cols[e], s1 = cols[e + 4];
    const float n0 = nrm[e], n1 = nrm[e + 4];
    const ushort4 h0 = *reinterpret_cast<const ushort4*>(hb + (size_t)s0 * CH + l * 4);
    const ushort4 h1 = *reinterpret_cast<const ushort4*>(hb + (size_t)s1 * CH + l * 4);
    a0 += n0 * bf2f(h0.x) + n1 * bf2f(h1.x);
    a1 += n0 * bf2f(h0.y) + n1 * bf2f(h1.y);
    a2 += n0 * bf2f(h0.z) + n1 * bf2f(h1.z);
    a3 += n0 * bf2f(h0.w) + n1 * bf2f(h1.w);
  }
  if (e < end) {
    const int s0 = cols[e];
    const float n0 = nrm[e];
    const ushort4 h0 = *reinterpret_cast<const ushort4*>(hb + (size_t)s0 * CH + l * 4);
    a0 += n0 * bf2f(h0.x); a1 += n0 * bf2f(h0.y);
    a2 += n0 * bf2f(h0.z); a3 += n0 * bf2f(h0.w);
  }
  *reinterpret_cast<float4*>(&red[w][l * 4]) = make_float4(a0, a1, a2, a3);
  __syncthreads();
  const float di = dinv[i];
  float sum = red[0][t] + red[1][t] + red[2][t] + red[3][t]
            + di * di * bf2f(hb[(size_t)i * CH + t]) + b1[t];
  out1[(size_t)i * CH + t] = fmaxf(sum, 0.0f);
}

// ---- GEMM2: h2[16384][16] = out1 @ W2[256][16] ----
__global__ __launch_bounds__(256)
void k_gemm2(const float* __restrict__ out1, const float* __restrict__ w2,
             float* __restrict__ h2) {
  __shared__ float xs[16][256];
  __shared__ float ws[256 * 16];
  const int t = threadIdx.x;
  const int n0 = blockIdx.x * 16;
#pragma unroll
  for (int i = 0; i < 16; ++i) ws[i * 256 + t] = w2[i * 256 + t];
#pragma unroll
  for (int i = 0; i < 16; ++i) xs[i][t] = out1[(size_t)(n0 + i) * CH + t];
  __syncthreads();
  const int node = t >> 4, k = t & 15;
  float acc = 0.f;
#pragma unroll 8
  for (int c = 0; c < 256; ++c) acc += xs[node][c] * ws[c * 16 + k];
  h2[(size_t)(n0 + node) * KC + k] = acc;
}

// ---- aggregation 2 (+b2): one wave per node ----
__global__ __launch_bounds__(256)
void k_agg2(const float* __restrict__ h2, const int* __restrict__ rowp,
            const int* __restrict__ cols, const float* __restrict__ nrm,
            const float* __restrict__ dinv, const float* __restrict__ b2,
            float* __restrict__ out) {
  const int i = blockIdx.x * 4 + (threadIdx.x >> 6);
  const int lane = threadIdx.x & 63;
  const int k = lane & 15, g = lane >> 4;
  const int beg = rowp[i], end = rowp[i + 1];
  float acc = 0.f;
  for (int e = beg + g; e < end; e += 4)
    acc += nrm[e] * h2[(size_t)cols[e] * KC + k];
  acc += __shfl_xor(acc, 16);
  acc += __shfl_xor(acc, 32);
  if (g == 0) {
    const float di = dinv[i];
    out[(size_t)i * KC + k] = acc + di * di * h2[(size_t)i * KC + k] + b2[k];
  }
}

extern "C" void kernel_launch(void* const* d_in, const int* in_sizes, int n_in,
                              void* d_out, int out_size, void* d_ws, size_t ws_size,
                              hipStream_t stream) {
  const float* x  = (const float*)d_in[0];
  const int*   ei = (const int*)d_in[1];
  const float* ew = (const float*)d_in[2];
  const float* w1 = (const float*)d_in[3];
  const float* b1 = (const float*)d_in[4];
  const float* w2 = (const float*)d_in[5];
  const float* b2 = (const float*)d_in[6];
  const int* src = ei;
  const int* dst = ei + NE;

  uint8_t* ws = (uint8_t*)d_ws;
  unsigned short* bpk = (unsigned short*)(ws + OFF_BP);
  float* hp   = (float*)(ws + OFF_HP);
  unsigned short* hb = (unsigned short*)(ws + OFF_HB);
  float* out1 = (float*)(ws + OFF_OUT1);
  float* h2   = (float*)(ws + OFF_H2);
  float* deg  = (float*)(ws + OFF_DEG);
  int*   cnt  = (int*)(ws + OFF_CNT);
  float* dinv = (float*)(ws + OFF_DINV);
  int*   rowp = (int*)(ws + OFF_ROWP);
  int*   curs = (int*)(ws + OFF_CUR);
  int*   cols = (int*)(ws + OFF_COLS);
  float* nrm  = (float*)(ws + OFF_NRM);
  float* out  = (float*)d_out;

  hipMemsetAsync(ws + OFF_DEG, 0, 131072, stream);  // deg + cnt

  k_bpack<<<dim3(256, 4), 256, 0, stream>>>(w1, bpk);
  k_deg <<<NE / 256, 256, 0, stream>>>(dst, ew, deg, cnt);
  k_scan<<<1, 256, 0, stream>>>(cnt, deg, rowp, curs, dinv);
  k_fill<<<NE / 256, 256, 0, stream>>>(src, dst, ew, dinv, curs, cols, nrm);
  k_gemm1<<<1024, 256, 0, stream>>>(x, bpk, hp);
  k_hred<<<NN * CH / (256 * 8), 256, 0, stream>>>(hp, hb);
  k_agg1<<<NN, 256, 0, stream>>>(hb, rowp, cols, nrm, dinv, b1, out1);
  k_gemm2<<<NN / 16, 256, 0, stream>>>(out1, w2, h2);
  k_agg2<<<NN / 4, 256, 0, stream>>>(h2, rowp, cols, nrm, dinv, b2, out);
}